// Round 20
// baseline (936.350 us; speedup 1.0000x reference)
//
#include <hip/hip_runtime.h>

#define NN 100000
#define EE 400000
#define HH 512
#define NB_SCAN 98   // ceil(NN/1024)

typedef __attribute__((ext_vector_type(8))) short short8;
typedef __attribute__((ext_vector_type(8))) unsigned short ushort8;
typedef __attribute__((ext_vector_type(4))) float f32x4;

__device__ inline unsigned short f2b(float f) {   // f32 -> bf16 RNE
    unsigned int u = __float_as_uint(f);
    return (unsigned short)((u + 0x7fffu + ((u >> 16) & 1u)) >> 16);
}
__device__ inline float b2f(unsigned short b) {
    return __uint_as_float(((unsigned int)b) << 16);
}

// ================= CSR build =================
__global__ void histo_deg(const int* __restrict__ dst, int* __restrict__ deg) {
    int e = blockIdx.x * blockDim.x + threadIdx.x;
    if (e < EE) atomicAdd(&deg[dst[e]], 1);
}

__global__ void scan_reduce(const int* __restrict__ deg, int* __restrict__ blockSums) {
    __shared__ int s[256];
    int b = blockIdx.x, t = threadIdx.x;
    int base = b * 1024 + t * 4;
    int v = 0;
    #pragma unroll
    for (int j = 0; j < 4; ++j) { int i = base + j; if (i < NN) v += deg[i]; }
    s[t] = v; __syncthreads();
    for (int off = 128; off > 0; off >>= 1) {
        if (t < off) s[t] += s[t + off];
        __syncthreads();
    }
    if (t == 0) blockSums[b] = s[0];
}

__global__ void scan_top(int* __restrict__ blockSums, int* __restrict__ start) {
    __shared__ int s[128];
    int t = threadIdx.x;
    s[t] = (t < NB_SCAN) ? blockSums[t] : 0;
    __syncthreads();
    for (int off = 1; off < 128; off <<= 1) {
        int u = (t >= off) ? s[t - off] : 0;
        __syncthreads();
        s[t] += u;
        __syncthreads();
    }
    if (t < NB_SCAN) blockSums[t] = (t == 0) ? 0 : s[t - 1];  // exclusive
    if (t == 0) start[NN] = EE;
}

__global__ void scan_down(const int* __restrict__ deg, const int* __restrict__ blockSums,
                          int* __restrict__ start, int* __restrict__ cursor) {
    __shared__ int s[256];
    int b = blockIdx.x, t = threadIdx.x;
    int base = b * 1024 + t * 4;
    int v[4]; int sum = 0;
    #pragma unroll
    for (int j = 0; j < 4; ++j) {
        int i = base + j;
        v[j] = (i < NN) ? deg[i] : 0;
        sum += v[j];
    }
    s[t] = sum; __syncthreads();
    for (int off = 1; off < 256; off <<= 1) {
        int u = (t >= off) ? s[t - off] : 0;
        __syncthreads();
        s[t] += u;
        __syncthreads();
    }
    int excl = blockSums[b] + ((t == 0) ? 0 : s[t - 1]);
    #pragma unroll
    for (int j = 0; j < 4; ++j) {
        int i = base + j;
        if (i < NN) { start[i] = excl; cursor[i] = excl; excl += v[j]; }
    }
}

__global__ void csr_fill(const int* __restrict__ src, const int* __restrict__ dst,
                         int* __restrict__ cursor, int* __restrict__ eidx) {
    int e = blockIdx.x * blockDim.x + threadIdx.x;
    if (e < EE) {
        int p = atomicAdd(&cursor[dst[e]], 1);
        eidx[p] = src[e];
    }
}

// ================= Weight transpose -> PACKED tiles (all 6 in one launch) =================
// Packed layout (per 512x512 matrix, "row" = output col n):
//   pos(n,k) = (n>>7)*65536 + ((k>>5)&15)*4096 + (n&127)*32
//            + ((((k>>3)&3) ^ ((n>>1)&3)) << 3) + (k&7)
__global__ void w_transpose_all(
    const float* __restrict__ w0, const float* __restrict__ w1,
    const float* __restrict__ w2, const float* __restrict__ w3,
    const float* __restrict__ w4, const float* __restrict__ w5,
    unsigned short* __restrict__ wt)   // 6 x 262144 contiguous
{
    int m = blockIdx.x >> 10;
    int idx = ((blockIdx.x & 1023) << 8) + threadIdx.x;  // n*512 + k
    int n = idx >> 9, k = idx & 511;
    const float* w = (m == 0) ? w0 : (m == 1) ? w1 : (m == 2) ? w2
                   : (m == 3) ? w3 : (m == 4) ? w4 : w5;
    size_t pos = ((size_t)(n >> 7) << 16) + (((k >> 5) & 15) << 12) + ((n & 127) << 5)
               + (((((k >> 3) & 3) ^ ((n >> 1) & 3))) << 3) + (k & 7);
    wt[(size_t)m * 262144 + pos] = f2b(w[(size_t)k * HH + n]);
}

// ================= Aggregation: bf16 gather, PACKED output =================
__global__ __launch_bounds__(256) void gather_rows_b(
    const unsigned short* __restrict__ xb, const int* __restrict__ start,
    const int* __restrict__ eidx, unsigned short* __restrict__ agg)
{
    int node = blockIdx.x * 4 + (threadIdx.x >> 6);
    if (node >= NN) return;
    int l = threadIdx.x & 63;
    int c0 = l << 3;                    // 8 bf16 per lane
    float a[8] = {0.f,0.f,0.f,0.f,0.f,0.f,0.f,0.f};
    int e0 = start[node], e1 = start[node + 1];
    int e = e0;
    for (; e + 4 <= e1; e += 4) {
        int s0 = eidx[e], s1 = eidx[e + 1], s2 = eidx[e + 2], s3 = eidx[e + 3];
        ushort8 v0 = *(const ushort8*)(xb + (size_t)s0 * HH + c0);
        ushort8 v1 = *(const ushort8*)(xb + (size_t)s1 * HH + c0);
        ushort8 v2 = *(const ushort8*)(xb + (size_t)s2 * HH + c0);
        ushort8 v3 = *(const ushort8*)(xb + (size_t)s3 * HH + c0);
        #pragma unroll
        for (int j = 0; j < 8; ++j)
            a[j] += (b2f(v0[j]) + b2f(v1[j])) + (b2f(v2[j]) + b2f(v3[j]));
    }
    for (; e < e1; ++e) {
        ushort8 v = *(const ushort8*)(xb + (size_t)eidx[e] * HH + c0);
        #pragma unroll
        for (int j = 0; j < 8; ++j) a[j] += b2f(v[j]);
    }
    ushort8 o;
    #pragma unroll
    for (int j = 0; j < 8; ++j) o[j] = f2b(a[j]);
    size_t pa = ((size_t)(node >> 7) << 16) + ((size_t)(l >> 2) << 12)
              + ((size_t)(node & 127) << 5)
              + ((size_t)(((l & 3) ^ ((node >> 1) & 3)) << 3));
    *(ushort8*)(agg + pa) = o;
}

// Layer-1 scalar aggregate via CSR
__global__ void gather_scalar(const float* __restrict__ x, const int* __restrict__ start,
                              const int* __restrict__ eidx, float* __restrict__ agg0) {
    int i = blockIdx.x * blockDim.x + threadIdx.x;
    if (i >= NN) return;
    float s = 0.f;
    int e1 = start[i + 1];
    for (int e = start[i]; e < e1; ++e) s += x[eidx[e]];
    agg0[i] = s;
}

// x1[i][h] = relu(agg0[i]*w_rel[h] + b[h] + x[i]*w_root[h]); bf16 unpacked
__global__ void layer1_expand(const float* __restrict__ x,
                              const float* __restrict__ agg0,
                              const float* __restrict__ w_rel,
                              const float* __restrict__ b,
                              const float* __restrict__ w_root,
                              unsigned short* __restrict__ x1b) {
    int idx = blockIdx.x * blockDim.x + threadIdx.x;
    int i = idx >> 7;
    if (i >= NN) return;
    int q = (idx & 127) << 2;
    float a = agg0[i], xv = x[i];
    float4 wr = *(const float4*)&w_rel[q];
    float4 bb = *(const float4*)&b[q];
    float4 wt = *(const float4*)&w_root[q];
    float4 o;
    o.x = fmaxf(fmaf(a, wr.x, fmaf(xv, wt.x, bb.x)), 0.f);
    o.y = fmaxf(fmaf(a, wr.y, fmaf(xv, wt.y, bb.y)), 0.f);
    o.z = fmaxf(fmaf(a, wr.z, fmaf(xv, wt.z, bb.z)), 0.f);
    o.w = fmaxf(fmaf(a, wr.w, fmaf(xv, wt.w, bb.w)), 0.f);
    ushort4 ob = { f2b(o.x), f2b(o.y), f2b(o.z), f2b(o.w) };
    *(ushort4*)&x1b[(size_t)i * HH + q] = ob;
}

// ================= Barrier-free single-wave MFMA GEMM =================
// out = (relu?)(AB@WrT^T + XBp@WoT^T + bias) + resid(bf16)
// One wave per block, 64x64 tile, BK=32, ZERO barriers: 3-buffer LDS rotation
// with counted s_waitcnt vmcnt(8) (8 gloads per K-step; depth-2 prefetch).
// Buffer-reuse safety is pure program order within the single wave.
// A 1st half / B: packed contiguous chunks. A 2nd half: strided x-stream.
__device__ inline void gload16(const void* g, void* l) {
    __builtin_amdgcn_global_load_lds(
        (const __attribute__((address_space(1))) unsigned int*)g,
        (__attribute__((address_space(3))) unsigned int*)l,
        16, 0, 0);
}

template<bool RELU, bool F32OUT>
__global__ __launch_bounds__(64) void gemm_wave(
    const unsigned short* __restrict__ AB, const unsigned short* __restrict__ XBp,
    const unsigned short* __restrict__ WrT, const unsigned short* __restrict__ WoT,
    const float* __restrict__ bias, const unsigned short* __restrict__ residb,
    float* __restrict__ out, unsigned short* __restrict__ outb)
{
    __shared__ unsigned short As[3 * 2048];   // 3 bufs x 64 rows x 32 k (4 KB each)
    __shared__ unsigned short Bs[3 * 2048];
    const int lane = threadIdx.x;

    // XCD-chunked mapping: 12504 blocks = 8 XCDs x 1563.
    const int bid = blockIdx.x;
    const int nid = (bid & 7) * 1563 + (bid >> 3);
    const int ntile = nid & 7;              // n-fastest -> A-panel L2 reuse
    const int mtile = nid >> 3;
    const int col0 = ntile << 6;
    const int row0 = mtile << 6;

    const int l16 = lane & 15, lq = lane >> 4;
    const int sColSwz = (((lane & 3) ^ ((lane >> 3) & 3)) << 3); // strided src k-slot
    const int xorslot = ((lq ^ ((lane >> 1) & 3)) << 3);         // read-side slot

    // Packed bases: 64-row tile = contiguous 4 KB half of a 128-row chunk.
    const unsigned short* pA = AB + ((size_t)(mtile >> 1) << 16) + ((mtile & 1) << 11);
    const size_t pBoff = ((size_t)(ntile >> 1) << 16) + ((ntile & 1) << 11);

    // Strided x-stream rows (clamped; stores guarded)
    int rowA[4];
    #pragma unroll
    for (int i = 0; i < 4; ++i) {
        int gr = row0 + i * 16 + (lane >> 2);
        rowA[i] = (gr >= NN) ? (NN - 1) : gr;
    }

    f32x4 acc[4][4];
    #pragma unroll
    for (int m = 0; m < 4; ++m)
        #pragma unroll
        for (int n = 0; n < 4; ++n) acc[m][n] = (f32x4){0.f,0.f,0.f,0.f};

    auto STAGE = [&](unsigned short* Asb, unsigned short* Bsb, int t) {
        const int c = t & 15;
        const unsigned short* srcB = ((t < 16) ? WrT : WoT) + pBoff + (c << 12);
        #pragma unroll
        for (int i = 0; i < 4; ++i)
            gload16(srcB + (i << 9) + (lane << 3), Bsb + (i << 9));
        if (t < 16) {
            const unsigned short* srcA = pA + (c << 12);
            #pragma unroll
            for (int i = 0; i < 4; ++i)
                gload16(srcA + (i << 9) + (lane << 3), Asb + (i << 9));
        } else {
            const int kk = c << 5;
            #pragma unroll
            for (int i = 0; i < 4; ++i)
                gload16(XBp + (size_t)rowA[i] * HH + kk + sColSwz, Asb + (i << 9));
        }
    };
    auto COMPUTE = [&](const unsigned short* Asb, const unsigned short* Bsb) {
        short8 af[4], bfv[4];
        #pragma unroll
        for (int m = 0; m < 4; ++m)
            af[m] = *(const short8*)(Asb + (m * 16 + l16) * 32 + xorslot);
        #pragma unroll
        for (int n = 0; n < 4; ++n)
            bfv[n] = *(const short8*)(Bsb + (n * 16 + l16) * 32 + xorslot);
        #pragma unroll
        for (int m = 0; m < 4; ++m)
            #pragma unroll
            for (int n = 0; n < 4; ++n)
                acc[m][n] = __builtin_amdgcn_mfma_f32_16x16x32_bf16(af[m], bfv[n], acc[m][n], 0, 0, 0);
    };

    unsigned short *A0 = As, *A1 = As + 2048, *A2 = As + 4096;
    unsigned short *B0 = Bs, *B1 = Bs + 2048, *B2 = Bs + 4096;

    // Prologue: depth-2 prefetch (16 loads in flight).
    STAGE(A0, B0, 0);
    STAGE(A1, B1, 1);

    // Main: iters 0..29 in groups of 3 (buffer rotation). No barriers.
    #pragma unroll 1
    for (int t = 0; t < 30; t += 3) {
        asm volatile("s_waitcnt vmcnt(8)" ::: "memory");   // tile t landed
        STAGE(A2, B2, t + 2);
        COMPUTE(A0, B0);
        asm volatile("s_waitcnt vmcnt(8)" ::: "memory");   // tile t+1 landed
        STAGE(A0, B0, t + 3);
        COMPUTE(A1, B1);
        asm volatile("s_waitcnt vmcnt(8)" ::: "memory");   // tile t+2 landed
        if (t + 4 < 32) STAGE(A1, B1, t + 4);
        COMPUTE(A2, B2);
    }
    // Tail: tiles 30 (buf0) and 31 (buf1).
    asm volatile("s_waitcnt vmcnt(8)" ::: "memory");
    COMPUTE(A0, B0);
    asm volatile("s_waitcnt vmcnt(0)" ::: "memory");
    COMPUTE(A1, B1);

    // Epilogue: + bias (+relu) + bf16 resid; store f32 or bf16
    float bias_n[4];
    #pragma unroll
    for (int n = 0; n < 4; ++n) bias_n[n] = bias[col0 + n * 16 + l16];

    #pragma unroll
    for (int m = 0; m < 4; ++m) {
        #pragma unroll
        for (int j = 0; j < 4; ++j) {
            int row = row0 + m * 16 + lq * 4 + j;
            if (row >= NN) continue;
            #pragma unroll
            for (int n = 0; n < 4; ++n) {
                int col = col0 + n * 16 + l16;
                size_t off = (size_t)row * HH + col;
                float v = acc[m][n][j] + bias_n[n];
                if (RELU) v = fmaxf(v, 0.f);
                v += b2f(residb[off]);
                if (F32OUT) out[off] = v;
                else        outb[off] = f2b(v);
            }
        }
    }
}

extern "C" void kernel_launch(void* const* d_in, const int* in_sizes, int n_in,
                              void* d_out, int out_size, void* d_ws, size_t ws_size,
                              hipStream_t stream) {
    const float* x   = (const float*)d_in[0];
    const int*   ei  = (const int*)d_in[1];
    const int*   src = ei;
    const int*   dst = ei + EE;
    const float* w_rel1  = (const float*)d_in[2];
    const float* b_rel1  = (const float*)d_in[3];
    const float* w_root1 = (const float*)d_in[4];
    const float* w_rel2  = (const float*)d_in[5];
    const float* b_rel2  = (const float*)d_in[6];
    const float* w_root2 = (const float*)d_in[7];
    const float* w_rel3  = (const float*)d_in[8];
    const float* b_rel3  = (const float*)d_in[9];
    const float* w_root3 = (const float*)d_in[10];
    const float* w_rel4  = (const float*)d_in[11];
    const float* b_rel4  = (const float*)d_in[12];
    const float* w_root4 = (const float*)d_in[13];

    const size_t NH  = (size_t)NN * HH;
    const size_t NHP = (size_t)100096 * HH;              // packed AGB (782 full rowblocks)
    unsigned short* XB   = (unsigned short*)d_ws;        // x1 bf16 (unpacked)
    unsigned short* XB2  = XB + NH;                      // x2 bf16 (unpacked)
    unsigned short* X3B  = XB2 + NH;                     // x3 bf16 (unpacked)
    unsigned short* AGB  = X3B + NH;                     // agg bf16 (PACKED, padded)
    unsigned short* WT   = AGB + NHP;                    // 6 packed bf16 weights
    float*          agg0 = (float*)(WT + 6 * 262144);
    int*            csr  = (int*)(agg0 + NN);
    int* deg       = csr;
    int* start     = csr + NN;
    int* cursor    = start + NN + 1;
    int* eidx      = cursor + NN;
    int* blockSums = eidx + EE;
    float* out = (float*)d_out;

    unsigned short* WrT2 = WT;
    unsigned short* WoT2 = WT + 1 * 262144;
    unsigned short* WrT3 = WT + 2 * 262144;
    unsigned short* WoT3 = WT + 3 * 262144;
    unsigned short* WrT4 = WT + 4 * 262144;
    unsigned short* WoT4 = WT + 5 * 262144;

    const int gGemm = 12504;  // 1563 m-tiles x 8 n-tiles (64x64), XCD-chunked

    // ---- CSR build ----
    hipMemsetAsync(deg, 0, NN * sizeof(int), stream);
    histo_deg<<<(EE + 255) / 256, 256, 0, stream>>>(dst, deg);
    scan_reduce<<<NB_SCAN, 256, 0, stream>>>(deg, blockSums);
    scan_top<<<1, 128, 0, stream>>>(blockSums, start);
    scan_down<<<NB_SCAN, 256, 0, stream>>>(deg, blockSums, start, cursor);
    csr_fill<<<(EE + 255) / 256, 256, 0, stream>>>(src, dst, cursor, eidx);

    // ---- Weights -> packed bf16 tiles (one launch) ----
    w_transpose_all<<<6144, 256, 0, stream>>>(
        w_rel2, w_root2, w_rel3, w_root3, w_rel4, w_root4, WT);

    // ---- Layer 1: x1 -> XB (bf16, unpacked) ----
    gather_scalar<<<(NN + 255) / 256, 256, 0, stream>>>(x, start, eidx, agg0);
    layer1_expand<<<50000, 256, 0, stream>>>(x, agg0, w_rel1, b_rel1, w_root1, XB);

    // ---- Layer 2: x2 = relu(conv(x1)) + x1 -> XB2 (bf16) ----
    gather_rows_b<<<25000, 256, 0, stream>>>(XB, start, eidx, AGB);
    gemm_wave<true, false><<<gGemm, 64, 0, stream>>>(
        AGB, XB, WrT2, WoT2, b_rel2, XB, nullptr, XB2);

    // ---- Layer 3: x3 = conv(x2) + x2 -> X3B (bf16) ----
    gather_rows_b<<<25000, 256, 0, stream>>>(XB2, start, eidx, AGB);
    gemm_wave<false, false><<<gGemm, 64, 0, stream>>>(
        AGB, XB2, WrT3, WoT3, b_rel3, XB2, nullptr, X3B);

    // ---- Layer 4: x4 = conv(x3) + x3 -> d_out (f32) ----
    gather_rows_b<<<25000, 256, 0, stream>>>(X3B, start, eidx, AGB);
    gemm_wave<false, true><<<gGemm, 64, 0, stream>>>(
        AGB, X3B, WrT4, WoT4, b_rel4, X3B, out, nullptr);
}

// Round 21
// 761.784 us; speedup vs baseline: 1.2292x; 1.2292x over previous
//
#include <hip/hip_runtime.h>

#define NN 100000
#define EE 400000
#define HH 512
#define NB_SCAN 98   // ceil(NN/1024)

typedef __attribute__((ext_vector_type(8))) short short8;
typedef __attribute__((ext_vector_type(8))) unsigned short ushort8;
typedef __attribute__((ext_vector_type(4))) float f32x4;

__device__ inline unsigned short f2b(float f) {   // f32 -> bf16 RNE
    unsigned int u = __float_as_uint(f);
    return (unsigned short)((u + 0x7fffu + ((u >> 16) & 1u)) >> 16);
}
__device__ inline float b2f(unsigned short b) {
    return __uint_as_float(((unsigned int)b) << 16);
}

// ================= CSR build =================
__global__ void histo_deg(const int* __restrict__ dst, int* __restrict__ deg) {
    int e = blockIdx.x * blockDim.x + threadIdx.x;
    if (e < EE) atomicAdd(&deg[dst[e]], 1);
}

__global__ void scan_reduce(const int* __restrict__ deg, int* __restrict__ blockSums) {
    __shared__ int s[256];
    int b = blockIdx.x, t = threadIdx.x;
    int base = b * 1024 + t * 4;
    int v = 0;
    #pragma unroll
    for (int j = 0; j < 4; ++j) { int i = base + j; if (i < NN) v += deg[i]; }
    s[t] = v; __syncthreads();
    for (int off = 128; off > 0; off >>= 1) {
        if (t < off) s[t] += s[t + off];
        __syncthreads();
    }
    if (t == 0) blockSums[b] = s[0];
}

__global__ void scan_top(int* __restrict__ blockSums, int* __restrict__ start) {
    __shared__ int s[128];
    int t = threadIdx.x;
    s[t] = (t < NB_SCAN) ? blockSums[t] : 0;
    __syncthreads();
    for (int off = 1; off < 128; off <<= 1) {
        int u = (t >= off) ? s[t - off] : 0;
        __syncthreads();
        s[t] += u;
        __syncthreads();
    }
    if (t < NB_SCAN) blockSums[t] = (t == 0) ? 0 : s[t - 1];  // exclusive
    if (t == 0) start[NN] = EE;
}

__global__ void scan_down(const int* __restrict__ deg, const int* __restrict__ blockSums,
                          int* __restrict__ start, int* __restrict__ cursor) {
    __shared__ int s[256];
    int b = blockIdx.x, t = threadIdx.x;
    int base = b * 1024 + t * 4;
    int v[4]; int sum = 0;
    #pragma unroll
    for (int j = 0; j < 4; ++j) {
        int i = base + j;
        v[j] = (i < NN) ? deg[i] : 0;
        sum += v[j];
    }
    s[t] = sum; __syncthreads();
    for (int off = 1; off < 256; off <<= 1) {
        int u = (t >= off) ? s[t - off] : 0;
        __syncthreads();
        s[t] += u;
        __syncthreads();
    }
    int excl = blockSums[b] + ((t == 0) ? 0 : s[t - 1]);
    #pragma unroll
    for (int j = 0; j < 4; ++j) {
        int i = base + j;
        if (i < NN) { start[i] = excl; cursor[i] = excl; excl += v[j]; }
    }
}

__global__ void csr_fill(const int* __restrict__ src, const int* __restrict__ dst,
                         int* __restrict__ cursor, int* __restrict__ eidx) {
    int e = blockIdx.x * blockDim.x + threadIdx.x;
    if (e < EE) {
        int p = atomicAdd(&cursor[dst[e]], 1);
        eidx[p] = src[e];
    }
}

// ================= Weight transpose -> PACKED tiles (all 6 in one launch) =================
// Packed layout (per 512x512 matrix, "row" = output col n):
//   pos(n,k) = (n>>7)*65536 + ((k>>5)&15)*4096 + (n&127)*32
//            + ((((k>>3)&3) ^ ((n>>1)&3)) << 3) + (k&7)
// A chunk (rowblock, kchunk) is 8 KB contiguous and byte-identical to the
// GEMM's LDS tile (XOR slot swizzle baked in).
__global__ void w_transpose_all(
    const float* __restrict__ w0, const float* __restrict__ w1,
    const float* __restrict__ w2, const float* __restrict__ w3,
    const float* __restrict__ w4, const float* __restrict__ w5,
    unsigned short* __restrict__ wt)   // 6 x 262144 contiguous
{
    int m = blockIdx.x >> 10;
    int idx = ((blockIdx.x & 1023) << 8) + threadIdx.x;  // n*512 + k
    int n = idx >> 9, k = idx & 511;
    const float* w = (m == 0) ? w0 : (m == 1) ? w1 : (m == 2) ? w2
                   : (m == 3) ? w3 : (m == 4) ? w4 : w5;
    size_t pos = ((size_t)(n >> 7) << 16) + (((k >> 5) & 15) << 12) + ((n & 127) << 5)
               + (((((k >> 3) & 3) ^ ((n >> 1) & 3))) << 3) + (k & 7);
    wt[(size_t)m * 262144 + pos] = f2b(w[(size_t)k * HH + n]);
}

// ================= Aggregation: bf16 gather, PACKED output =================
// Input xb is unpacked [node][512]; output agg is packed (GEMM A-operand only).
__global__ __launch_bounds__(256) void gather_rows_b(
    const unsigned short* __restrict__ xb, const int* __restrict__ start,
    const int* __restrict__ eidx, unsigned short* __restrict__ agg)
{
    int node = blockIdx.x * 4 + (threadIdx.x >> 6);
    if (node >= NN) return;
    int l = threadIdx.x & 63;
    int c0 = l << 3;                    // 8 bf16 per lane (k = l*8 .. l*8+7)
    float a[8] = {0.f,0.f,0.f,0.f,0.f,0.f,0.f,0.f};
    int e0 = start[node], e1 = start[node + 1];
    int e = e0;
    for (; e + 4 <= e1; e += 4) {
        int s0 = eidx[e], s1 = eidx[e + 1], s2 = eidx[e + 2], s3 = eidx[e + 3];
        ushort8 v0 = *(const ushort8*)(xb + (size_t)s0 * HH + c0);
        ushort8 v1 = *(const ushort8*)(xb + (size_t)s1 * HH + c0);
        ushort8 v2 = *(const ushort8*)(xb + (size_t)s2 * HH + c0);
        ushort8 v3 = *(const ushort8*)(xb + (size_t)s3 * HH + c0);
        #pragma unroll
        for (int j = 0; j < 8; ++j)
            a[j] += (b2f(v0[j]) + b2f(v1[j])) + (b2f(v2[j]) + b2f(v3[j]));
    }
    for (; e < e1; ++e) {
        ushort8 v = *(const ushort8*)(xb + (size_t)eidx[e] * HH + c0);
        #pragma unroll
        for (int j = 0; j < 8; ++j) a[j] += b2f(v[j]);
    }
    ushort8 o;
    #pragma unroll
    for (int j = 0; j < 8; ++j) o[j] = f2b(a[j]);
    // packed write: chunk = l>>2, logical slot = l&3, swizzled by (node>>1)&3
    size_t pa = ((size_t)(node >> 7) << 16) + ((size_t)(l >> 2) << 12)
              + ((size_t)(node & 127) << 5)
              + ((size_t)(((l & 3) ^ ((node >> 1) & 3)) << 3));
    *(ushort8*)(agg + pa) = o;
}

// Layer-1 scalar aggregate via CSR
__global__ void gather_scalar(const float* __restrict__ x, const int* __restrict__ start,
                              const int* __restrict__ eidx, float* __restrict__ agg0) {
    int i = blockIdx.x * blockDim.x + threadIdx.x;
    if (i >= NN) return;
    float s = 0.f;
    int e1 = start[i + 1];
    for (int e = start[i]; e < e1; ++e) s += x[eidx[e]];
    agg0[i] = s;
}

// x1[i][h] = relu(agg0[i]*w_rel[h] + b[h] + x[i]*w_root[h]); bf16 unpacked
__global__ void layer1_expand(const float* __restrict__ x,
                              const float* __restrict__ agg0,
                              const float* __restrict__ w_rel,
                              const float* __restrict__ b,
                              const float* __restrict__ w_root,
                              unsigned short* __restrict__ x1b) {
    int idx = blockIdx.x * blockDim.x + threadIdx.x;
    int i = idx >> 7;
    if (i >= NN) return;
    int q = (idx & 127) << 2;
    float a = agg0[i], xv = x[i];
    float4 wr = *(const float4*)&w_rel[q];
    float4 bb = *(const float4*)&b[q];
    float4 wt = *(const float4*)&w_root[q];
    float4 o;
    o.x = fmaxf(fmaf(a, wr.x, fmaf(xv, wt.x, bb.x)), 0.f);
    o.y = fmaxf(fmaf(a, wr.y, fmaf(xv, wt.y, bb.y)), 0.f);
    o.z = fmaxf(fmaf(a, wr.z, fmaf(xv, wt.z, bb.z)), 0.f);
    o.w = fmaxf(fmaf(a, wr.w, fmaf(xv, wt.w, bb.w)), 0.f);
    ushort4 ob = { f2b(o.x), f2b(o.y), f2b(o.z), f2b(o.w) };
    *(ushort4*)&x1b[(size_t)i * HH + q] = ob;
}

// ================= MFMA GEMM (R17 structure; packed AGB + packed weights) =================
// out = (relu?)(AB@WrT^T + XBp@WoT^T + bias) + resid(bf16)
// 128x128 tile, BK=32, 4 waves, dbuf, one barrier per K-step, 3 blocks/CU.
// Staging: A 1st K-half (packed AGB) and B (packed weights) are CONTIGUOUS
// 1 KB gload16s; A 2nd K-half (unpacked x-stream) keeps the strided path.
// LDS layout/read side unchanged (swizzle baked into packed data).
__device__ inline void gload16(const void* g, void* l) {
    __builtin_amdgcn_global_load_lds(
        (const __attribute__((address_space(1))) unsigned int*)g,
        (__attribute__((address_space(3))) unsigned int*)l,
        16, 0, 0);
}

template<bool RELU, bool F32OUT>
__global__ __launch_bounds__(256, 3) void gemm_mfma(
    const unsigned short* __restrict__ AB, const unsigned short* __restrict__ XBp,
    const unsigned short* __restrict__ WrT, const unsigned short* __restrict__ WoT,
    const float* __restrict__ bias, const unsigned short* __restrict__ residb,
    float* __restrict__ out, unsigned short* __restrict__ outb)
{
    __shared__ unsigned short As[2 * 128 * 32];  // [buf][row][k], k-slots swizzled
    __shared__ unsigned short Bs[2 * 128 * 32];  // [buf][col][k]
    const int tid  = threadIdx.x;
    const int wave = tid >> 6, lane = tid & 63;

    // Bijective XCD-chunked mapping: 3128 blocks = 8 XCDs x 391.
    const int bid = blockIdx.x;
    const int nid = (bid & 7) * 391 + (bid >> 3);
    const int col0 = (nid & 3) << 7;   // n-tile fastest -> A-panel L2 reuse
    const int row0 = (nid >> 2) << 7;
    const int rb = nid >> 2;           // row-block index
    const int cb = nid & 3;            // col-block index

    const int wr = wave >> 1, wc = wave & 1; // wave's 64x64 quadrant
    const int l16 = lane & 15, lq = lane >> 4;
    const int sRow = lane >> 2;                                  // strided staging row
    const int sColSwz = (((lane & 3) ^ ((lane >> 3) & 3)) << 3); // strided src k-slot
    const int xorslot = ((lq ^ ((lane >> 1) & 3)) << 3);         // read-side slot

    int rowA[2];
    #pragma unroll
    for (int i = 0; i < 2; ++i) {
        int chunk = (wave << 1) + i;
        int gr = row0 + chunk * 16 + sRow;
        rowA[i] = (gr >= NN) ? (NN - 1) : gr;
    }

    f32x4 acc[4][4];
    #pragma unroll
    for (int m = 0; m < 4; ++m)
        #pragma unroll
        for (int n = 0; n < 4; ++n) acc[m][n] = (f32x4){0.f,0.f,0.f,0.f};

    auto STAGE = [&](unsigned short* Asb, unsigned short* Bsb, int t) {
        const int c = t & 15;
        // B: packed, contiguous 8 KB chunk
        {
            const unsigned short* Wp = (t < 16) ? WrT : WoT;
            const unsigned short* srcB = Wp + ((size_t)cb << 16) + (c << 12);
            #pragma unroll
            for (int i = 0; i < 2; ++i) {
                int j = (wave << 1) + i;
                gload16(srcB + (j << 9) + (lane << 3), Bsb + (j << 9));
            }
        }
        if (t < 16) {
            // A 1st half: packed AGB, contiguous
            const unsigned short* srcA = AB + ((size_t)rb << 16) + (c << 12);
            #pragma unroll
            for (int i = 0; i < 2; ++i) {
                int j = (wave << 1) + i;
                gload16(srcA + (j << 9) + (lane << 3), Asb + (j << 9));
            }
        } else {
            // A 2nd half: unpacked x-stream, strided (pre-swizzled source)
            const int kk = c << 5;
            #pragma unroll
            for (int i = 0; i < 2; ++i) {
                int chunk = (wave << 1) + i;
                gload16(XBp + (size_t)rowA[i] * HH + kk + sColSwz, Asb + chunk * 512);
            }
        }
    };
    auto COMPUTE = [&](const unsigned short* Asb, const unsigned short* Bsb) {
        short8 af[4], bfv[4];
        #pragma unroll
        for (int m = 0; m < 4; ++m)
            af[m] = *(const short8*)(Asb + (wr * 64 + m * 16 + l16) * 32 + xorslot);
        #pragma unroll
        for (int n = 0; n < 4; ++n)
            bfv[n] = *(const short8*)(Bsb + (wc * 64 + n * 16 + l16) * 32 + xorslot);
        #pragma unroll
        for (int m = 0; m < 4; ++m)
            #pragma unroll
            for (int n = 0; n < 4; ++n)
                acc[m][n] = __builtin_amdgcn_mfma_f32_16x16x32_bf16(af[m], bfv[n], acc[m][n], 0, 0, 0);
    };

    unsigned short *A0 = As, *A1 = As + 4096, *B0 = Bs, *B1 = Bs + 4096;
    STAGE(A0, B0, 0);
    __syncthreads();
    #pragma unroll 1
    for (int t = 0; t < 32; t += 2) {
        STAGE(A1, B1, t + 1);
        COMPUTE(A0, B0);
        __syncthreads();
        if (t + 2 < 32) STAGE(A0, B0, t + 2);
        COMPUTE(A1, B1);
        __syncthreads();
    }

    float bias_n[4];
    #pragma unroll
    for (int n = 0; n < 4; ++n) bias_n[n] = bias[col0 + wc * 64 + n * 16 + l16];

    #pragma unroll
    for (int m = 0; m < 4; ++m) {
        #pragma unroll
        for (int j = 0; j < 4; ++j) {
            int row = row0 + wr * 64 + m * 16 + lq * 4 + j;
            if (row >= NN) continue;
            #pragma unroll
            for (int n = 0; n < 4; ++n) {
                int col = col0 + wc * 64 + n * 16 + l16;
                size_t off = (size_t)row * HH + col;
                float v = acc[m][n][j] + bias_n[n];
                if (RELU) v = fmaxf(v, 0.f);
                v += b2f(residb[off]);
                if (F32OUT) out[off] = v;
                else        outb[off] = f2b(v);
            }
        }
    }
}

extern "C" void kernel_launch(void* const* d_in, const int* in_sizes, int n_in,
                              void* d_out, int out_size, void* d_ws, size_t ws_size,
                              hipStream_t stream) {
    const float* x   = (const float*)d_in[0];
    const int*   ei  = (const int*)d_in[1];
    const int*   src = ei;
    const int*   dst = ei + EE;
    const float* w_rel1  = (const float*)d_in[2];
    const float* b_rel1  = (const float*)d_in[3];
    const float* w_root1 = (const float*)d_in[4];
    const float* w_rel2  = (const float*)d_in[5];
    const float* b_rel2  = (const float*)d_in[6];
    const float* w_root2 = (const float*)d_in[7];
    const float* w_rel3  = (const float*)d_in[8];
    const float* b_rel3  = (const float*)d_in[9];
    const float* w_root3 = (const float*)d_in[10];
    const float* w_rel4  = (const float*)d_in[11];
    const float* b_rel4  = (const float*)d_in[12];
    const float* w_root4 = (const float*)d_in[13];

    const size_t NH  = (size_t)NN * HH;
    const size_t NHP = (size_t)100096 * HH;              // packed AGB (782 full rowblocks)
    unsigned short* XB   = (unsigned short*)d_ws;        // x1 bf16 (unpacked)
    unsigned short* XB2  = XB + NH;                      // x2 bf16 (unpacked)
    unsigned short* X3B  = XB2 + NH;                     // x3 bf16 (unpacked)
    unsigned short* AGB  = X3B + NH;                     // agg bf16 (PACKED, padded)
    unsigned short* WT   = AGB + NHP;                    // 6 packed bf16 weights
    float*          agg0 = (float*)(WT + 6 * 262144);
    int*            csr  = (int*)(agg0 + NN);
    int* deg       = csr;
    int* start     = csr + NN;
    int* cursor    = start + NN + 1;
    int* eidx      = cursor + NN;
    int* blockSums = eidx + EE;
    float* out = (float*)d_out;

    unsigned short* WrT2 = WT;
    unsigned short* WoT2 = WT + 1 * 262144;
    unsigned short* WrT3 = WT + 2 * 262144;
    unsigned short* WoT3 = WT + 3 * 262144;
    unsigned short* WrT4 = WT + 4 * 262144;
    unsigned short* WoT4 = WT + 5 * 262144;

    const int gGemm = 3128;  // 782 m-tiles x 4 n-tiles (128x128), XCD-chunked in-kernel

    // ---- CSR build ----
    hipMemsetAsync(deg, 0, NN * sizeof(int), stream);
    histo_deg<<<(EE + 255) / 256, 256, 0, stream>>>(dst, deg);
    scan_reduce<<<NB_SCAN, 256, 0, stream>>>(deg, blockSums);
    scan_top<<<1, 128, 0, stream>>>(blockSums, start);
    scan_down<<<NB_SCAN, 256, 0, stream>>>(deg, blockSums, start, cursor);
    csr_fill<<<(EE + 255) / 256, 256, 0, stream>>>(src, dst, cursor, eidx);

    // ---- Weights -> packed bf16 tiles (one launch) ----
    w_transpose_all<<<6144, 256, 0, stream>>>(
        w_rel2, w_root2, w_rel3, w_root3, w_rel4, w_root4, WT);

    // ---- Layer 1: x1 -> XB (bf16, unpacked) ----
    gather_scalar<<<(NN + 255) / 256, 256, 0, stream>>>(x, start, eidx, agg0);
    layer1_expand<<<50000, 256, 0, stream>>>(x, agg0, w_rel1, b_rel1, w_root1, XB);

    // ---- Layer 2: x2 = relu(conv(x1)) + x1 -> XB2 (bf16) ----
    gather_rows_b<<<25000, 256, 0, stream>>>(XB, start, eidx, AGB);
    gemm_mfma<true, false><<<gGemm, 256, 0, stream>>>(
        AGB, XB, WrT2, WoT2, b_rel2, XB, nullptr, XB2);

    // ---- Layer 3: x3 = conv(x2) + x2 -> X3B (bf16) ----
    gather_rows_b<<<25000, 256, 0, stream>>>(XB2, start, eidx, AGB);
    gemm_mfma<false, false><<<gGemm, 256, 0, stream>>>(
        AGB, XB2, WrT3, WoT3, b_rel3, XB2, nullptr, X3B);

    // ---- Layer 4: x4 = conv(x3) + x3 -> d_out (f32) ----
    gather_rows_b<<<25000, 256, 0, stream>>>(X3B, start, eidx, AGB);
    gemm_mfma<false, true><<<gGemm, 256, 0, stream>>>(
        AGB, X3B, WrT4, WoT4, b_rel4, X3B, out, nullptr);
}